// Round 7
// baseline (280.004 us; speedup 1.0000x reference)
//
#include <hip/hip_runtime.h>

// EquivariantLinear: out[pos, c, m] = pw * sum_k x[pos, k, m] * W_{l(m)}[k, c]
// pos = 32768, C_IN = C_OUT = 256, FEAT = 9 (irreps 1,3,5), pw = 1/16.
// R9: chain-concurrency test with ZERO duplicated memory work.
//  - POSB=8, 4096 blocks x 256 threads (4 waves, 1/SIMD). Each wave owns
//    64 channels (ct=0..3). m-planes packed 2-per-16-row MFMA tile within an
//    irrep: T0{m0} T1{m1,m2} T2{m3} T3{m4,m5} T4{m6,m7} T5{m8} (1.33x MFMA,
//    idle pipe). acc = 4ct x 6T = 96 regs; launch_bounds(256,3) -> 3
//    blocks/CU = 3 independent load->compute->store chains per CU
//    (R8: ~1.5). Total HBM loads/converts/ds-writes/stores == R8 exactly.
//  - Keeps R7 36-B-unit coalesced loads, cvt_pk converts, R8 nt stores,
//    LDS-staged coalesced output (2 chunks of 2 ct, wave-local slices).

typedef float f32x4 __attribute__((ext_vector_type(4)));
typedef float f32x4u __attribute__((ext_vector_type(4), aligned(4)));
typedef short s16x8 __attribute__((ext_vector_type(8)));

#define POSB 8                       // positions per block
#define XS_KS 264                    // padded k-stride (elems)
#define XS_MS (POSB * XS_KS)         // 2112 elems per m-plane
#define SMEM_BYTES (9 * XS_MS * 2)   // 38016 B -> 3 blocks/CU (114 KB)
#define STG_ROW 292                  // out-stage row stride (floats); 288 used
// per-wave out-stage chunk: 8*292*4 = 9344 B; 4 waves = 37376 <= 38016

__device__ __forceinline__ unsigned short f2bf(float f) {
  unsigned u = __float_as_uint(f);
  return (unsigned short)((u + 0x7FFFu + ((u >> 16) & 1u)) >> 16);
}

__device__ __forceinline__ unsigned cvt_pk_bf16(float lo, float hi) {
  unsigned r;
  asm("v_cvt_pk_bf16_f32 %0, %1, %2" : "=v"(r) : "v"(lo), "v"(hi));
  return r;
}

// ---- prep: W^T bf16 image in ws: wt[irr][c][k] = pw * w_irr[k][c] ----
__global__ void prep_w(const float* __restrict__ w0, const float* __restrict__ w1,
                       const float* __restrict__ w2, unsigned short* __restrict__ wt) {
  const int b = blockIdx.x;
  const int irr = b / 16;
  const int tile = b % 16;
  const int k0 = (tile >> 2) << 6;
  const int c0 = (tile & 3) << 6;
  const float* w = (irr == 0) ? w0 : ((irr == 1) ? w1 : w2);
  __shared__ float lt[64 * 65];
  const int t = threadIdx.x;
#pragma unroll
  for (int i = 0; i < 16; ++i) {
    int e = t + (i << 8);
    int kk = e >> 6, cc = e & 63;
    lt[cc * 65 + kk] = w[(k0 + kk) * 256 + (c0 + cc)];
  }
  __syncthreads();
#pragma unroll
  for (int i = 0; i < 16; ++i) {
    int e = t + (i << 8);
    int cc = e >> 6, kk = e & 63;
    wt[irr * 65536 + (c0 + cc) * 256 + (k0 + kk)] = f2bf(lt[cc * 65 + kk] * 0.0625f);
  }
}

// ---- main: 4096 blocks x 256 threads (4 waves), 3 blocks/CU ----
__global__ __launch_bounds__(256, 3) void eqlin_main(
    const float* __restrict__ x, const unsigned short* __restrict__ wt,
    float* __restrict__ out) {
  extern __shared__ char smem[];
  unsigned short* xs = reinterpret_cast<unsigned short*>(smem);  // [9][8][264] bf16

  const int t = threadIdx.x;
  const long long blk = blockIdx.x;
  const float* xb = x + blk * (POSB * 2304);

  // ---- stage x -> LDS bf16 [m][pos][k]: 2048 36-B units, 8 per thread ----
  {
    f32x4u va[8], vb[8];
    float vc[8];
#pragma unroll
    for (int i = 0; i < 8; ++i) {
      const float* s = xb + (t + (i << 8)) * 9;
      va[i] = *reinterpret_cast<const f32x4u*>(s);
      vb[i] = *reinterpret_cast<const f32x4u*>(s + 4);
      vc[i] = s[8];
    }
#pragma unroll
    for (int i = 0; i < 8; ++i) {
      const int u = t + (i << 8);
      const int pos = u >> 8;        // 0..7
      const int k = u & 255;
      unsigned short* base = xs + pos * XS_KS + k;
      unsigned p01 = cvt_pk_bf16(va[i][0], va[i][1]);
      unsigned p23 = cvt_pk_bf16(va[i][2], va[i][3]);
      unsigned p45 = cvt_pk_bf16(vb[i][0], vb[i][1]);
      unsigned p67 = cvt_pk_bf16(vb[i][2], vb[i][3]);
      base[0 * XS_MS] = (unsigned short)p01;
      base[1 * XS_MS] = (unsigned short)(p01 >> 16);
      base[2 * XS_MS] = (unsigned short)p23;
      base[3 * XS_MS] = (unsigned short)(p23 >> 16);
      base[4 * XS_MS] = (unsigned short)p45;
      base[5 * XS_MS] = (unsigned short)(p45 >> 16);
      base[6 * XS_MS] = (unsigned short)p67;
      base[7 * XS_MS] = (unsigned short)(p67 >> 16);
      base[8 * XS_MS] = f2bf(vc[i]);
    }
  }
  __syncthreads();

  const int w = t >> 6;           // 0..3
  const int l = t & 63;
  const int cr = l & 15;          // A row sel / B col (=c in 16-wide group)
  const int kg = (l >> 4) << 3;   // k-chunk base 0/8/16/24
  const int c0 = w << 6;          // 64 channels per wave

  // A tile bases: rows 0-7 -> plane pA (pos=cr), rows 8-15 -> plane pB
  const bool hi = (cr >= 8);
  const unsigned short* xrow = xs + (cr & 7) * XS_KS + kg;
  const unsigned short* xa[6] = {
      xrow + 0 * XS_MS,                    // T0 {0,0}
      xrow + (hi ? 2 : 1) * XS_MS,         // T1 {1,2}
      xrow + 3 * XS_MS,                    // T2 {3,3}
      xrow + (hi ? 5 : 4) * XS_MS,         // T3 {4,5}
      xrow + (hi ? 7 : 6) * XS_MS,         // T4 {6,7}
      xrow + 8 * XS_MS,                    // T5 {8,8}
  };

  const unsigned short* wtB = wt + (c0 + cr) * 256 + kg;  // + ct*4096

  f32x4 acc[4][6];  // [ct][tile]
#pragma unroll
  for (int ct = 0; ct < 4; ++ct)
#pragma unroll
    for (int T = 0; T < 6; ++T) acc[ct][T] = (f32x4){0.f, 0.f, 0.f, 0.f};

#pragma unroll 2
  for (int ks = 0; ks < 8; ++ks) {
    const int kk = ks << 5;
    s16x8 a0 = *reinterpret_cast<const s16x8*>(xa[0] + kk);
    s16x8 a1 = *reinterpret_cast<const s16x8*>(xa[1] + kk);
    s16x8 a2 = *reinterpret_cast<const s16x8*>(xa[2] + kk);
    s16x8 a3 = *reinterpret_cast<const s16x8*>(xa[3] + kk);
    s16x8 a4 = *reinterpret_cast<const s16x8*>(xa[4] + kk);
    s16x8 a5 = *reinterpret_cast<const s16x8*>(xa[5] + kk);
#pragma unroll
    for (int ct = 0; ct < 4; ++ct) {
      const unsigned short* wc = wtB + ct * 4096 + kk;
      s16x8 b0 = *reinterpret_cast<const s16x8*>(wc);            // irr0
      s16x8 b1 = *reinterpret_cast<const s16x8*>(wc + 65536);    // irr1
      s16x8 b2 = *reinterpret_cast<const s16x8*>(wc + 131072);   // irr2
      acc[ct][0] = __builtin_amdgcn_mfma_f32_16x16x32_bf16(a0, b0, acc[ct][0], 0, 0, 0);
      acc[ct][1] = __builtin_amdgcn_mfma_f32_16x16x32_bf16(a1, b1, acc[ct][1], 0, 0, 0);
      acc[ct][2] = __builtin_amdgcn_mfma_f32_16x16x32_bf16(a2, b1, acc[ct][2], 0, 0, 0);
      acc[ct][3] = __builtin_amdgcn_mfma_f32_16x16x32_bf16(a3, b2, acc[ct][3], 0, 0, 0);
      acc[ct][4] = __builtin_amdgcn_mfma_f32_16x16x32_bf16(a4, b2, acc[ct][4], 0, 0, 0);
      acc[ct][5] = __builtin_amdgcn_mfma_f32_16x16x32_bf16(a5, b2, acc[ct][5], 0, 0, 0);
    }
  }
  __syncthreads();  // xs fully consumed by ALL waves; stage may alias it

  // ---- per-wave out-stage, 2 chunks of 2 ct (wave-internal sync only) ----
  float* stgw = reinterpret_cast<float*>(smem) + w * (POSB * STG_ROW);
  const int g = l >> 4;                 // 0..3; rows = g*4+j
  const int posb = (g & 1) << 2;        // pos base 0/4 (pos = row & 7)

  const int pAt[6] = {0, 1, 3, 4, 6, 8};
  const int pBt[6] = {0, 2, 3, 5, 7, 8};

  f32x4* o4 = reinterpret_cast<f32x4*>(out);

#pragma unroll
  for (int h = 0; h < 2; ++h) {         // chunk: cts {2h, 2h+1}
    // scatter acc -> stgw[pos][(ch*16+cr)*9 + m]
#pragma unroll
    for (int ch = 0; ch < 2; ++ch) {
#pragma unroll
      for (int T = 0; T < 6; ++T) {
        const int m = (g < 2) ? pAt[T] : pBt[T];
        if (g < 2 || pAt[T] != pBt[T]) {  // rows 8-15 of pad tiles: duplicates
#pragma unroll
          for (int j = 0; j < 4; ++j)
            stgw[(posb + j) * STG_ROW + ((ch << 4) + cr) * 9 + m] = acc[2 * h + ch][T][j];
        }
      }
    }
    asm volatile("s_waitcnt lgkmcnt(0)" ::: "memory");
    // coalesced nt float4 store of this wave's 8pos x 32c x 9m chunk
#pragma unroll
    for (int q = 0; q < 9; ++q) {
      const int e = l + (q << 6);                 // 0..575 float4s
      const int pos = (int)((unsigned)e / 72u);
      const int rem = e - pos * 72;
      f32x4 v = *reinterpret_cast<const f32x4*>(stgw + pos * STG_ROW + (rem << 2));
      __builtin_nontemporal_store(
          v, &o4[(blk * POSB + pos) * 576 + w * 144 + h * 72 + rem]);
    }
    asm volatile("s_waitcnt lgkmcnt(0)" ::: "memory");  // drain before next chunk
  }
}

extern "C" void kernel_launch(void* const* d_in, const int* in_sizes, int n_in,
                              void* d_out, int out_size, void* d_ws, size_t ws_size,
                              hipStream_t stream) {
  const float* x = (const float*)d_in[0];
  const float* w0 = (const float*)d_in[1];
  const float* w1 = (const float*)d_in[2];
  const float* w2 = (const float*)d_in[3];
  unsigned short* wt = (unsigned short*)d_ws;  // 3*256*256 bf16 = 384 KB
  float* out = (float*)d_out;

  prep_w<<<48, 256, 0, stream>>>(w0, w1, w2, wt);

  (void)hipFuncSetAttribute(reinterpret_cast<const void*>(eqlin_main),
                            hipFuncAttributeMaxDynamicSharedMemorySize, SMEM_BYTES);
  eqlin_main<<<4096, 256, SMEM_BYTES, stream>>>(x, wt, out);
}

// Round 8
// 192.399 us; speedup vs baseline: 1.4553x; 1.4553x over previous
//
#include <hip/hip_runtime.h>

// EquivariantLinear: out[pos, c, m] = pw * sum_k x[pos, k, m] * W_{l(m)}[k, c]
// pos = 32768, C_IN = C_OUT = 256, FEAT = 9 (irreps 1,3,5), pw = 1/16.
// R10: cross-tile software pipeline WITHOUT store drains.
//  - 512 blocks x 512 thr; each block runs NT=4 pos-tiles (POSB=16).
//  - LDS = 2 x 76032 B double buffer (152 KB -> 1 block/CU).
//  - Per iter: [A] issue tile t+1 global loads -> regs (72 VGPR held)
//              [B] compute tile t from buf[p] (ds_read + MFMA, wt from L2)
//              [BAR: lgkmcnt(0) + raw s_barrier -- NO vmcnt drain]
//              [C] out-stage tile t via buf[p] alias (scatter/read/nt-store,
//                  stores never waited on)
//              [D] cvt + ds_write tile t+1 into buf[p^1]
//              [BAR]
//    __syncthreads is NEVER used in the loop: its implicit vmcnt(0) drained
//    the nt stores every iteration (R3's failure mechanism). Raw s_barrier +
//    lgkmcnt(0) gives LDS ordering; prefetch-load waits are compiler-counted
//    vmcnt on first register use in D. Max outstanding vmcnt/wave ~60 < 63.
//  - Stage = R7 36-B units + cvt_pk; stores = R8 nt; compute = R2.

typedef float f32x4 __attribute__((ext_vector_type(4)));
typedef float f32x4u __attribute__((ext_vector_type(4), aligned(4)));
typedef short s16x8 __attribute__((ext_vector_type(8)));

#define POSB 16                      // positions per tile
#define XS_KS 264                    // padded k-stride (elems)
#define XS_MS (POSB * XS_KS)         // 4224 elems per m-plane
#define BUF_BYTES (9 * XS_MS * 2)    // 76032 B per buffer
#define SMEM_BYTES (2 * BUF_BYTES)   // 152064 B -> 1 block/CU
#define STG_ROW 148                  // out-stage row stride (floats); 144 used
#define NT 4                         // tiles per block; 512 blocks x 4 = 2048
#define TILE_FLOATS (POSB * 2304)    // 36864

__device__ __forceinline__ unsigned short f2bf(float f) {
  unsigned u = __float_as_uint(f);
  return (unsigned short)((u + 0x7FFFu + ((u >> 16) & 1u)) >> 16);
}

__device__ __forceinline__ unsigned cvt_pk_bf16(float lo, float hi) {
  unsigned r;
  asm("v_cvt_pk_bf16_f32 %0, %1, %2" : "=v"(r) : "v"(lo), "v"(hi));
  return r;
}

// raw barrier: LDS ordering only, no vmcnt drain (stores stay in flight)
__device__ __forceinline__ void bar_nodrain() {
  asm volatile("s_waitcnt lgkmcnt(0)\n\ts_barrier" ::: "memory");
}

// ---- prep: W^T bf16 image in ws: wt[irr][c][k] = pw * w_irr[k][c] ----
__global__ void prep_w(const float* __restrict__ w0, const float* __restrict__ w1,
                       const float* __restrict__ w2, unsigned short* __restrict__ wt) {
  const int b = blockIdx.x;
  const int irr = b / 16;
  const int tile = b % 16;
  const int k0 = (tile >> 2) << 6;
  const int c0 = (tile & 3) << 6;
  const float* w = (irr == 0) ? w0 : ((irr == 1) ? w1 : w2);
  __shared__ float lt[64 * 65];
  const int t = threadIdx.x;
#pragma unroll
  for (int i = 0; i < 16; ++i) {
    int e = t + (i << 8);
    int kk = e >> 6, cc = e & 63;
    lt[cc * 65 + kk] = w[(k0 + kk) * 256 + (c0 + cc)];
  }
  __syncthreads();
#pragma unroll
  for (int i = 0; i < 16; ++i) {
    int e = t + (i << 8);
    int cc = e >> 6, kk = e & 63;
    wt[irr * 65536 + (c0 + cc) * 256 + (k0 + kk)] = f2bf(lt[cc * 65 + kk] * 0.0625f);
  }
}

// issue the 24 global loads of one tile's 8 thread-units (36-B units)
__device__ __forceinline__ void load8(const float* __restrict__ xb, int t,
                                      f32x4u* va, f32x4u* vb, float* vc) {
#pragma unroll
  for (int i = 0; i < 8; ++i) {
    const float* s = xb + (t + (i << 9)) * 9;
    va[i] = *reinterpret_cast<const f32x4u*>(s);
    vb[i] = *reinterpret_cast<const f32x4u*>(s + 4);
    vc[i] = s[8];
  }
}

// convert + scatter 8 units into xs [m][pos][k] (ds_write_b16, 2B stride)
__device__ __forceinline__ void stage8(unsigned short* __restrict__ xs, int t,
                                       const f32x4u* va, const f32x4u* vb,
                                       const float* vc) {
#pragma unroll
  for (int i = 0; i < 8; ++i) {
    const int u = t + (i << 9);
    const int pos = u >> 8;        // 0..15
    const int k = u & 255;
    unsigned short* base = xs + pos * XS_KS + k;
    unsigned p01 = cvt_pk_bf16(va[i][0], va[i][1]);
    unsigned p23 = cvt_pk_bf16(va[i][2], va[i][3]);
    unsigned p45 = cvt_pk_bf16(vb[i][0], vb[i][1]);
    unsigned p67 = cvt_pk_bf16(vb[i][2], vb[i][3]);
    base[0 * XS_MS] = (unsigned short)p01;
    base[1 * XS_MS] = (unsigned short)(p01 >> 16);
    base[2 * XS_MS] = (unsigned short)p23;
    base[3 * XS_MS] = (unsigned short)(p23 >> 16);
    base[4 * XS_MS] = (unsigned short)p45;
    base[5 * XS_MS] = (unsigned short)(p45 >> 16);
    base[6 * XS_MS] = (unsigned short)p67;
    base[7 * XS_MS] = (unsigned short)(p67 >> 16);
    base[8 * XS_MS] = f2bf(vc[i]);
  }
}

// ---- main: 512 blocks x 512 threads (8 waves), 1 block/CU, NT=4 tiles ----
__global__ __launch_bounds__(512, 2) void eqlin_main(
    const float* __restrict__ x, const unsigned short* __restrict__ wt,
    float* __restrict__ out) {
  extern __shared__ char smem[];

  const int t = threadIdx.x;
  const long long blk = blockIdx.x;
  const float* xbase = x + blk * (NT * TILE_FLOATS);

  const int w = t >> 6;
  const int l = t & 63;
  const int cr = l & 15;          // A row (=pos) / B col (=c in tile)
  const int kg = (l >> 4) << 3;   // k-chunk base 0/8/16/24
  const int c0 = w << 5;          // 32 channels per wave
  const unsigned short* wtB = wt + (c0 + cr) * 256 + kg;

  f32x4u va[8], vb[8];            // in-flight tile (held across compute)
  float vc[8];

  // ---- prologue: load + stage tile 0 into buf0 ----
  load8(xbase, t, va, vb, vc);
  stage8(reinterpret_cast<unsigned short*>(smem), t, va, vb, vc);
  bar_nodrain();

#pragma unroll 2
  for (int it = 0; it < NT; ++it) {
    const int p = it & 1;
    const unsigned short* xsb =
        reinterpret_cast<const unsigned short*>(smem + p * BUF_BYTES);

    // [A] issue next tile's global loads (land during compute)
    if (it + 1 < NT) load8(xbase + (it + 1) * TILE_FLOATS, t, va, vb, vc);

    // [B] compute tile it from buf[p]
    const unsigned short* xsA = xsb + cr * XS_KS + kg;

    f32x4 accA[4][2];  // m = 0..3
#pragma unroll
    for (int m = 0; m < 4; ++m)
#pragma unroll
      for (int ct = 0; ct < 2; ++ct) accA[m][ct] = (f32x4){0.f, 0.f, 0.f, 0.f};

#pragma unroll 2
    for (int ks = 0; ks < 8; ++ks) {
      const int kk = ks << 5;
      s16x8 b00 = *reinterpret_cast<const s16x8*>(wtB + kk);
      s16x8 b01 = *reinterpret_cast<const s16x8*>(wtB + 4096 + kk);
      s16x8 b10 = *reinterpret_cast<const s16x8*>(wtB + 65536 + kk);
      s16x8 b11 = *reinterpret_cast<const s16x8*>(wtB + 65536 + 4096 + kk);
      {
        s16x8 a = *reinterpret_cast<const s16x8*>(xsA + kk);
        accA[0][0] = __builtin_amdgcn_mfma_f32_16x16x32_bf16(a, b00, accA[0][0], 0, 0, 0);
        accA[0][1] = __builtin_amdgcn_mfma_f32_16x16x32_bf16(a, b01, accA[0][1], 0, 0, 0);
      }
#pragma unroll
      for (int m = 1; m < 4; ++m) {
        s16x8 a = *reinterpret_cast<const s16x8*>(xsA + m * XS_MS + kk);
        accA[m][0] = __builtin_amdgcn_mfma_f32_16x16x32_bf16(a, b10, accA[m][0], 0, 0, 0);
        accA[m][1] = __builtin_amdgcn_mfma_f32_16x16x32_bf16(a, b11, accA[m][1], 0, 0, 0);
      }
    }

    f32x4 accB[5][2];  // m = 4..8 (irr2)
#pragma unroll
    for (int m = 0; m < 5; ++m)
#pragma unroll
      for (int ct = 0; ct < 2; ++ct) accB[m][ct] = (f32x4){0.f, 0.f, 0.f, 0.f};

#pragma unroll 2
    for (int ks = 0; ks < 8; ++ks) {
      const int kk = ks << 5;
      s16x8 b20 = *reinterpret_cast<const s16x8*>(wtB + 2 * 65536 + kk);
      s16x8 b21 = *reinterpret_cast<const s16x8*>(wtB + 2 * 65536 + 4096 + kk);
#pragma unroll
      for (int m = 0; m < 5; ++m) {
        s16x8 a = *reinterpret_cast<const s16x8*>(xsA + (m + 4) * XS_MS + kk);
        accB[m][0] = __builtin_amdgcn_mfma_f32_16x16x32_bf16(a, b20, accB[m][0], 0, 0, 0);
        accB[m][1] = __builtin_amdgcn_mfma_f32_16x16x32_bf16(a, b21, accB[m][1], 0, 0, 0);
      }
    }
    bar_nodrain();  // all waves done reading buf[p]; it becomes out-stage scratch

    // [C] out-stage tile it via per-wave slice of buf[p]; nt stores fire-and-forget
    float* stgw = reinterpret_cast<float*>(smem + p * BUF_BYTES) + w * (POSB * STG_ROW);
    const int posb = (l >> 4) << 2;
    f32x4* o4 = reinterpret_cast<f32x4*>(out) + (blk * NT + it) * 9216 + w * 72;

#pragma unroll
    for (int ct = 0; ct < 2; ++ct) {
#pragma unroll
      for (int m = 0; m < 9; ++m) {
#pragma unroll
        for (int j = 0; j < 4; ++j) {
          float v = (m < 4) ? accA[m][ct][j] : accB[m - 4][ct][j];
          stgw[(posb + j) * STG_ROW + cr * 9 + m] = v;
        }
      }
      asm volatile("s_waitcnt lgkmcnt(0)" ::: "memory");
#pragma unroll
      for (int q = 0; q < 9; ++q) {
        const int e = l + (q << 6);                 // 0..575 float4s
        const int pos = (int)((unsigned)e / 36u);
        const int rem = e - pos * 36;
        f32x4 v = *reinterpret_cast<const f32x4*>(stgw + pos * STG_ROW + (rem << 2));
        __builtin_nontemporal_store(v, &o4[pos * 576 + ct * 36 + rem]);
      }
      asm volatile("s_waitcnt lgkmcnt(0)" ::: "memory");  // reads done before next ct scatter
    }

    // [D] convert + stage prefetched tile into buf[p^1] (compiler-counted vmcnt
    //     on first va/vb/vc use; disjoint from buf[p] out-stage region)
    if (it + 1 < NT) {
      stage8(reinterpret_cast<unsigned short*>(smem + (p ^ 1) * BUF_BYTES), t, va, vb, vc);
    }
    bar_nodrain();  // buf[p^1] ready; output stores remain in flight
  }
}

extern "C" void kernel_launch(void* const* d_in, const int* in_sizes, int n_in,
                              void* d_out, int out_size, void* d_ws, size_t ws_size,
                              hipStream_t stream) {
  const float* x = (const float*)d_in[0];
  const float* w0 = (const float*)d_in[1];
  const float* w1 = (const float*)d_in[2];
  const float* w2 = (const float*)d_in[3];
  unsigned short* wt = (unsigned short*)d_ws;  // 3*256*256 bf16 = 384 KB
  float* out = (float*)d_out;

  prep_w<<<48, 256, 0, stream>>>(w0, w1, w2, wt);

  (void)hipFuncSetAttribute(reinterpret_cast<const void*>(eqlin_main),
                            hipFuncAttributeMaxDynamicSharedMemorySize, SMEM_BYTES);
  eqlin_main<<<512, 512, SMEM_BYTES, stream>>>(x, wt, out);
}